// Round 4
// baseline (289.670 us; speedup 1.0000x reference)
//
#include <hip/hip_runtime.h>
#include <math.h>

#define EPSF 1e-7f
#define NTHREADS 256

// anchors / stride, exact binary fractions
__device__ __constant__ float d_anch[3][3][2] = {
    {{10.f/8.f,  13.f/8.f},  {16.f/8.f,  30.f/8.f},  {33.f/8.f,  23.f/8.f}},
    {{30.f/16.f, 61.f/16.f}, {62.f/16.f, 45.f/16.f}, {59.f/16.f, 119.f/16.f}},
    {{116.f/32.f,90.f/32.f}, {156.f/32.f,198.f/32.f},{373.f/32.f,326.f/32.f}},
};

__device__ __forceinline__ float bce0(float x) {           // bce(x, 0)
    return fmaxf(x, 0.0f) + log1pf(expf(-fabsf(x)));
}
__device__ __forceinline__ float bcef(float x, float t) {  // full bce
    return fmaxf(x, 0.0f) - x * t + log1pf(expf(-fabsf(x)));
}
__device__ __forceinline__ float sigm(float x) {
    return 1.0f / (1.0f + expf(-x));
}

__device__ __forceinline__ float block_reduce(float v, float* s) {
    s[threadIdx.x] = v;
    __syncthreads();
    for (int st = NTHREADS / 2; st > 0; st >>= 1) {
        if (threadIdx.x < st) s[threadIdx.x] += s[threadIdx.x + st];
        __syncthreads();
    }
    float r = s[0];
    __syncthreads();
    return r;
}

// ---------------------------------------------------------------------------
// K1: zero tobj + done counter, streaming obj BCE term bce(x,0) per cell.
// No inter-block dependencies. grid = ceil(N/256).
// ---------------------------------------------------------------------------
__global__ void stream_kernel(const float* __restrict__ pred0,
                              const float* __restrict__ pred1,
                              const float* __restrict__ pred2,
                              float* __restrict__ tobj,
                              float* __restrict__ objpart,
                              int* __restrict__ done,
                              int n0, int n1, int n2)
{
    int idx = blockIdx.x * NTHREADS + threadIdx.x;
    int N = n0 + n1 + n2;
    float acc = 0.0f;
    if (idx < N) {
        tobj[idx] = 0.0f;
        const float* pred; int cell; float w;
        if (idx < n0)           { pred = pred0; cell = idx;            w = 4.0f / (float)n0; }
        else if (idx < n0 + n1) { pred = pred1; cell = idx - n0;       w = 1.0f / (float)n1; }
        else                    { pred = pred2; cell = idx - n0 - n1;  w = 0.4f / (float)n2; }
        float x = pred[(size_t)cell * 85 + 4];
        acc = w * bce0(x);
    }
    if (idx == 0) *done = 0;
    __shared__ float s[NTHREADS];
    float r = block_reduce(acc, s);
    if (threadIdx.x == 0) objpart[blockIdx.x] = r;
}

// ---------------------------------------------------------------------------
// K2: all per-entry work, wave-per-entry (4 waves/block), then last-block
// final reduction writes the scalar loss.
//   lobj = objsum - sum(telescoped w*x*(new-old))  [= sum w*x*tobj_final]
// ---------------------------------------------------------------------------
__global__ void entry_kernel(const float* __restrict__ pred0,
                             const float* __restrict__ pred1,
                             const float* __restrict__ pred2,
                             const float* __restrict__ targets,
                             int nt, int bpl2,
                             float* __restrict__ tobj_base,
                             const float* __restrict__ objpart, int nb1,
                             float* __restrict__ blockpart,  // [grid][4]
                             int* __restrict__ done,
                             float* __restrict__ out,
                             int n0, int n1, int n2, int B)
{
    int layer = blockIdx.x / bpl2;
    int sub   = blockIdx.x % bpl2;
    int wid   = threadIdx.x >> 6;
    int lane  = threadIdx.x & 63;
    int perLayer = 15 * nt;
    int eL = sub * 4 + wid;

    const float* pred; float* tobj; int H, W; float wl;
    if (layer == 0)      { pred = pred0; tobj = tobj_base;           H = 80; W = 80; wl = 4.0f / (float)n0; }
    else if (layer == 1) { pred = pred1; tobj = tobj_base + n0;      H = 40; W = 40; wl = 1.0f / (float)n1; }
    else                 { pred = pred2; tobj = tobj_base + n0 + n1; H = 20; W = 20; wl = 0.4f / (float)n2; }

    float lbox = 0.0f, cnt = 0.0f, corr = 0.0f, clsacc = 0.0f;

    if (eL < perLayer) {
        int t = eL % nt;
        int a = (eL / nt) % 3;
        int o = eL / (nt * 3);

        const float* tg = targets + t * 6;
        float tb = tg[0], tc = tg[1];
        float gx = tg[2] * (float)W, gy = tg[3] * (float)H;
        float gw = tg[4] * (float)W, gh = tg[5] * (float)H;

        float aw = d_anch[layer][a][0], ah = d_anch[layer][a][1];
        float rw = gw / (aw + 1e-16f), rh = gh / (ah + 1e-16f);
        float rmax = fmaxf(fmaxf(rw, 1.0f / rw), fmaxf(rh, 1.0f / rh));
        bool aok = rmax < 4.0f;

        float fxi = floorf(gx), fyi = floorf(gy);
        float fx = gx - fxi, fy = gy - fyi;
        bool selo;
        switch (o) {
            case 0: selo = true; break;
            case 1: selo = (fx > 0.5f) && (fxi < (float)(W - 1)); break;
            case 2: selo = (fy > 0.5f) && (fyi < (float)(H - 1)); break;
            case 3: selo = (fx < 0.5f) && (fxi > 0.0f); break;
            default: selo = (fy < 0.5f) && (fyi > 0.0f); break;
        }

        if (aok && selo) {
            float ox = (o == 1) ? 1.0f : (o == 3) ? -1.0f : 0.0f;
            float oy = (o == 2) ? 1.0f : (o == 4) ? -1.0f : 0.0f;
            float gex = gx - ox, gey = gy - oy;
            int gix = min(max((int)floorf(gex), 0), W - 1);
            int giy = min(max((int)floorf(gey), 0), H - 1);
            float txc = gex - (float)gix, tyc = gey - (float)giy;
            float tx1 = txc - gw * 0.5f, ty1 = tyc - gh * 0.5f;
            float tx2 = txc + gw * 0.5f, ty2 = tyc + gh * 0.5f;

            int b = (int)tb, cls = (int)tc;
            int cell = (int)(((((size_t)b * 3 + a) * H + giy) * W + gix));
            const float* pm = pred + (size_t)cell * 85;

            // scalar part computed redundantly on all 64 lanes (broadcast loads)
            float p0 = pm[0], p1v = pm[1], p2v = pm[2], p3 = pm[3];
            float pxc = sigm(p0) * 2.0f - 0.5f;
            float pyc = sigm(p1v) * 2.0f - 0.5f;
            float sw = sigm(p2v) * 2.0f;
            float sh = sigm(p3) * 2.0f;
            float pw = sw * sw * aw, ph = sh * sh * ah;
            float px1 = pxc - pw * 0.5f, py1 = pyc - ph * 0.5f;
            float px2 = pxc + pw * 0.5f, py2 = pyc + ph * 0.5f;

            float ix1 = fmaxf(px1, tx1), iy1 = fmaxf(py1, ty1);
            float ix2 = fminf(px2, tx2), iy2 = fminf(py2, ty2);
            float inter = fmaxf(ix2 - ix1, 0.0f) * fmaxf(iy2 - iy1, 0.0f);
            float a1 = (px2 - px1) * (py2 - py1);
            float a2 = (tx2 - tx1) * (ty2 - ty1);
            float uni = a1 + a2 - inter + EPSF;
            float iou = inter / uni;
            float ex1 = fminf(px1, tx1), ey1 = fminf(py1, ty1);
            float ex2 = fmaxf(px2, tx2), ey2 = fmaxf(py2, ty2);
            float cw = ex2 - ex1, chh = ey2 - ey1;
            float c2 = cw * cw + chh * chh + EPSF;
            float dx = px1 + px2 - tx1 - tx2;
            float dy = py1 + py2 - ty1 - ty2;
            float rho2 = (dx * dx + dy * dy) * 0.25f;
            float w1 = px2 - px1, h1 = py2 - py1;
            float w2 = tx2 - tx1, h2 = ty2 - ty1;
            float dat = atanf(w2 / (h2 + EPSF)) - atanf(w1 / (h1 + EPSF));
            float v = 0.40528473f * dat * dat;   // 4/pi^2
            float alpha = v / (1.0f - iou + v + EPSF);
            float ciou = iou - rho2 / c2 - alpha * v;

            if (lane == 0) {
                lbox = 1.0f - ciou;
                cnt = 1.0f;
                // telescoping max: sum of w*x*(new-old) over all entries
                // equals w*x*tobj_final per cell, any interleaving.
                float vobj = fmaxf(ciou, 0.0f);
                unsigned int oldb = atomicMax((unsigned int*)&tobj[cell],
                                              __float_as_uint(vobj));
                float old = __uint_as_float(oldb);
                float nw = fmaxf(vobj, old);
                corr = wl * pm[4] * (nw - old);
            }

            // class BCE: coalesced within the wave
            float xc = pm[5 + lane];
            clsacc = bcef(xc, (lane == cls) ? 1.0f : 0.0f);
            if (lane < 16) {
                float xc2 = pm[69 + lane];
                clsacc += bcef(xc2, ((64 + lane) == cls) ? 1.0f : 0.0f);
            }
        }
    }

    __shared__ float s[NTHREADS];
    float rb = block_reduce(lbox, s);
    float rc = block_reduce(cnt, s);
    float rl = block_reduce(clsacc, s);
    float rr = block_reduce(corr, s);
    if (threadIdx.x == 0) {
        float* p = blockpart + (size_t)blockIdx.x * 4;
        p[0] = rb; p[1] = rc; p[2] = rl; p[3] = rr;
    }

    // ---- last-block final reduction ----
    __shared__ int sLast;
    __threadfence();
    if (threadIdx.x == 0) {
        int old = atomicAdd(done, 1);
        sLast = (old == (int)gridDim.x - 1) ? 1 : 0;
    }
    __syncthreads();
    if (!sLast) return;
    __threadfence();

    int tid = threadIdx.x;
    float vsum = 0.0f;
    for (int i = tid; i < nb1; i += NTHREADS) vsum += objpart[i];
    float objsum = block_reduce(vsum, s);

    float corrsum;
    {
        float v2 = 0.0f;
        int nbk = 3 * bpl2;
        for (int i = tid; i < nbk; i += NTHREADS) v2 += blockpart[(size_t)i * 4 + 3];
        corrsum = block_reduce(v2, s);
    }

    float r_lb[3], r_cnt[3], r_cls[3];
    for (int L = 0; L < 3; ++L) {
        float v2 = 0.0f;
        for (int i = tid; i < bpl2; i += NTHREADS) v2 += blockpart[(size_t)(L * bpl2 + i) * 4 + 0];
        r_lb[L] = block_reduce(v2, s);
        v2 = 0.0f;
        for (int i = tid; i < bpl2; i += NTHREADS) v2 += blockpart[(size_t)(L * bpl2 + i) * 4 + 1];
        r_cnt[L] = block_reduce(v2, s);
        v2 = 0.0f;
        for (int i = tid; i < bpl2; i += NTHREADS) v2 += blockpart[(size_t)(L * bpl2 + i) * 4 + 2];
        r_cls[L] = block_reduce(v2, s);
    }

    if (tid == 0) {
        float lobj = objsum - corrsum;
        float lb = 0.0f, lc = 0.0f;
        for (int L = 0; L < 3; ++L) {
            if (r_cnt[L] > 0.0f) {
                lb += r_lb[L] / fmaxf(r_cnt[L], 1.0f);
                lc += r_cls[L] / fmaxf(r_cnt[L] * 80.0f, 1.0f);
            }
        }
        out[0] = (0.05f * lb + lobj + 0.5f * lc) * (float)B;
    }
}

extern "C" void kernel_launch(void* const* d_in, const int* in_sizes, int n_in,
                              void* d_out, int out_size, void* d_ws, size_t ws_size,
                              hipStream_t stream) {
    const float* pred0 = (const float*)d_in[0];
    const float* pred1 = (const float*)d_in[1];
    const float* pred2 = (const float*)d_in[2];
    const float* targets = (const float*)d_in[3];

    int B = in_sizes[0] / (3 * 80 * 80 * 85);
    int nt = in_sizes[3] / 6;
    int n0 = B * 3 * 80 * 80;
    int n1 = B * 3 * 40 * 40;
    int n2 = B * 3 * 20 * 20;
    int N = n0 + n1 + n2;
    int NB1 = (N + NTHREADS - 1) / NTHREADS;
    int perLayer = 15 * nt;
    int bpl2 = (perLayer + 3) / 4;          // 4 waves (entries) per block
    int grid2 = 3 * bpl2;

    // workspace layout (all float-aligned; done counter at the end)
    float* tobj = (float*)d_ws;
    float* objpart = tobj + N;
    float* blockpart = objpart + NB1;
    int* done = (int*)(blockpart + (size_t)grid2 * 4);

    stream_kernel<<<NB1, NTHREADS, 0, stream>>>(
        pred0, pred1, pred2, tobj, objpart, done, n0, n1, n2);
    entry_kernel<<<grid2, NTHREADS, 0, stream>>>(
        pred0, pred1, pred2, targets, nt, bpl2, tobj, objpart, NB1,
        blockpart, done, (float*)d_out, n0, n1, n2, B);
}

// Round 5
// 45.337 us; speedup vs baseline: 6.3893x; 6.3893x over previous
//
#include <hip/hip_runtime.h>
#include <math.h>

#define EPSF 1e-7f
#define NT1 256
#define NT2 1024   // entry kernel: 16 waves = 16 entries per block

// anchors / stride, exact binary fractions
__device__ __constant__ float d_anch[3][3][2] = {
    {{10.f/8.f,  13.f/8.f},  {16.f/8.f,  30.f/8.f},  {33.f/8.f,  23.f/8.f}},
    {{30.f/16.f, 61.f/16.f}, {62.f/16.f, 45.f/16.f}, {59.f/16.f, 119.f/16.f}},
    {{116.f/32.f,90.f/32.f}, {156.f/32.f,198.f/32.f},{373.f/32.f,326.f/32.f}},
};

__device__ __forceinline__ float bce0(float x) {           // bce(x, 0)
    return fmaxf(x, 0.0f) + log1pf(expf(-fabsf(x)));
}
__device__ __forceinline__ float bcef(float x, float t) {  // full bce
    return fmaxf(x, 0.0f) - x * t + log1pf(expf(-fabsf(x)));
}
__device__ __forceinline__ float sigm(float x) {
    return 1.0f / (1.0f + expf(-x));
}

template <int NT>
__device__ __forceinline__ float block_reduce(float v, float* s) {
    s[threadIdx.x] = v;
    __syncthreads();
    for (int st = NT / 2; st > 0; st >>= 1) {
        if (threadIdx.x < st) s[threadIdx.x] += s[threadIdx.x + st];
        __syncthreads();
    }
    float r = s[0];
    __syncthreads();
    return r;
}

// ---------------------------------------------------------------------------
// K1: zero tobj + streaming obj BCE term bce(x,0) per cell. No dependencies.
// ---------------------------------------------------------------------------
__global__ void stream_kernel(const float* __restrict__ pred0,
                              const float* __restrict__ pred1,
                              const float* __restrict__ pred2,
                              float* __restrict__ tobj,
                              float* __restrict__ objpart,
                              int n0, int n1, int n2)
{
    int idx = blockIdx.x * NT1 + threadIdx.x;
    int N = n0 + n1 + n2;
    float acc = 0.0f;
    if (idx < N) {
        tobj[idx] = 0.0f;
        const float* pred; int cell; float w;
        if (idx < n0)           { pred = pred0; cell = idx;            w = 4.0f / (float)n0; }
        else if (idx < n0 + n1) { pred = pred1; cell = idx - n0;       w = 1.0f / (float)n1; }
        else                    { pred = pred2; cell = idx - n0 - n1;  w = 0.4f / (float)n2; }
        float x = pred[(size_t)cell * 85 + 4];
        acc = w * bce0(x);
    }
    __shared__ float s[NT1];
    float r = block_reduce<NT1>(acc, s);
    if (threadIdx.x == 0) objpart[blockIdx.x] = r;
}

// ---------------------------------------------------------------------------
// K2: per-entry work, wave-per-entry (16 waves/block). Per-block partials:
// {lbox, cnt, cls, corr} where corr telescopes to  sum_cells w*x*tobj_final.
// NO device fences — ordering to K3 comes from the kernel boundary.
// ---------------------------------------------------------------------------
__global__ void entry_kernel(const float* __restrict__ pred0,
                             const float* __restrict__ pred1,
                             const float* __restrict__ pred2,
                             const float* __restrict__ targets,
                             int nt, int bpl2,
                             float* __restrict__ tobj_base,
                             float* __restrict__ blockpart,  // [grid][4]
                             int n0, int n1, int n2)
{
    int layer = blockIdx.x / bpl2;
    int sub   = blockIdx.x % bpl2;
    int wid   = threadIdx.x >> 6;
    int lane  = threadIdx.x & 63;
    int perLayer = 15 * nt;
    int eL = sub * 16 + wid;

    const float* pred; float* tobj; int H, W; float wl;
    if (layer == 0)      { pred = pred0; tobj = tobj_base;           H = 80; W = 80; wl = 4.0f / (float)n0; }
    else if (layer == 1) { pred = pred1; tobj = tobj_base + n0;      H = 40; W = 40; wl = 1.0f / (float)n1; }
    else                 { pred = pred2; tobj = tobj_base + n0 + n1; H = 20; W = 20; wl = 0.4f / (float)n2; }

    float lbox = 0.0f, cnt = 0.0f, corr = 0.0f, clsacc = 0.0f;

    if (eL < perLayer) {
        int t = eL % nt;
        int a = (eL / nt) % 3;
        int o = eL / (nt * 3);

        const float* tg = targets + t * 6;
        float tb = tg[0], tc = tg[1];
        float gx = tg[2] * (float)W, gy = tg[3] * (float)H;
        float gw = tg[4] * (float)W, gh = tg[5] * (float)H;

        float aw = d_anch[layer][a][0], ah = d_anch[layer][a][1];
        float rw = gw / (aw + 1e-16f), rh = gh / (ah + 1e-16f);
        float rmax = fmaxf(fmaxf(rw, 1.0f / rw), fmaxf(rh, 1.0f / rh));
        bool aok = rmax < 4.0f;

        float fxi = floorf(gx), fyi = floorf(gy);
        float fx = gx - fxi, fy = gy - fyi;
        bool selo;
        switch (o) {
            case 0: selo = true; break;
            case 1: selo = (fx > 0.5f) && (fxi < (float)(W - 1)); break;
            case 2: selo = (fy > 0.5f) && (fyi < (float)(H - 1)); break;
            case 3: selo = (fx < 0.5f) && (fxi > 0.0f); break;
            default: selo = (fy < 0.5f) && (fyi > 0.0f); break;
        }

        if (aok && selo) {
            float ox = (o == 1) ? 1.0f : (o == 3) ? -1.0f : 0.0f;
            float oy = (o == 2) ? 1.0f : (o == 4) ? -1.0f : 0.0f;
            float gex = gx - ox, gey = gy - oy;
            int gix = min(max((int)floorf(gex), 0), W - 1);
            int giy = min(max((int)floorf(gey), 0), H - 1);
            float txc = gex - (float)gix, tyc = gey - (float)giy;
            float tx1 = txc - gw * 0.5f, ty1 = tyc - gh * 0.5f;
            float tx2 = txc + gw * 0.5f, ty2 = tyc + gh * 0.5f;

            int b = (int)tb, cls = (int)tc;
            int cell = (int)(((((size_t)b * 3 + a) * H + giy) * W + gix));
            const float* pm = pred + (size_t)cell * 85;

            // scalar part redundantly on all lanes (broadcast loads, VALU idle)
            float p0 = pm[0], p1v = pm[1], p2v = pm[2], p3 = pm[3];
            float pxc = sigm(p0) * 2.0f - 0.5f;
            float pyc = sigm(p1v) * 2.0f - 0.5f;
            float sw = sigm(p2v) * 2.0f;
            float sh = sigm(p3) * 2.0f;
            float pw = sw * sw * aw, ph = sh * sh * ah;
            float px1 = pxc - pw * 0.5f, py1 = pyc - ph * 0.5f;
            float px2 = pxc + pw * 0.5f, py2 = pyc + ph * 0.5f;

            float ix1 = fmaxf(px1, tx1), iy1 = fmaxf(py1, ty1);
            float ix2 = fminf(px2, tx2), iy2 = fminf(py2, ty2);
            float inter = fmaxf(ix2 - ix1, 0.0f) * fmaxf(iy2 - iy1, 0.0f);
            float a1 = (px2 - px1) * (py2 - py1);
            float a2 = (tx2 - tx1) * (ty2 - ty1);
            float uni = a1 + a2 - inter + EPSF;
            float iou = inter / uni;
            float ex1 = fminf(px1, tx1), ey1 = fminf(py1, ty1);
            float ex2 = fmaxf(px2, tx2), ey2 = fmaxf(py2, ty2);
            float cw = ex2 - ex1, chh = ey2 - ey1;
            float c2 = cw * cw + chh * chh + EPSF;
            float dx = px1 + px2 - tx1 - tx2;
            float dy = py1 + py2 - ty1 - ty2;
            float rho2 = (dx * dx + dy * dy) * 0.25f;
            float w1 = px2 - px1, h1 = py2 - py1;
            float w2 = tx2 - tx1, h2 = ty2 - ty1;
            float dat = atanf(w2 / (h2 + EPSF)) - atanf(w1 / (h1 + EPSF));
            float v = 0.40528473f * dat * dat;   // 4/pi^2
            float alpha = v / (1.0f - iou + v + EPSF);
            float ciou = iou - rho2 / c2 - alpha * v;

            if (lane == 0) {
                lbox = 1.0f - ciou;
                cnt = 1.0f;
                // telescoping max: per cell, sum of w*x*(new-old) over all
                // entries equals w*x*tobj_final, for any atomic interleaving.
                float vobj = fmaxf(ciou, 0.0f);
                unsigned int oldb = atomicMax((unsigned int*)&tobj[cell],
                                              __float_as_uint(vobj));
                float old = __uint_as_float(oldb);
                float nw = fmaxf(vobj, old);
                corr = wl * pm[4] * (nw - old);
            }

            // class BCE: coalesced within the wave (ch 5..84)
            float xc = pm[5 + lane];
            clsacc = bcef(xc, (lane == cls) ? 1.0f : 0.0f);
            if (lane < 16) {
                float xc2 = pm[69 + lane];
                clsacc += bcef(xc2, ((64 + lane) == cls) ? 1.0f : 0.0f);
            }
        }
    }

    __shared__ float s[NT2];
    float rb = block_reduce<NT2>(lbox, s);
    float rc = block_reduce<NT2>(cnt, s);
    float rl = block_reduce<NT2>(clsacc, s);
    float rr = block_reduce<NT2>(corr, s);
    if (threadIdx.x == 0) {
        float* p = blockpart + (size_t)blockIdx.x * 4;
        p[0] = rb; p[1] = rc; p[2] = rl; p[3] = rr;
    }
}

// ---------------------------------------------------------------------------
// K3: final deterministic combine.
// ---------------------------------------------------------------------------
__global__ void final_kernel(const float* __restrict__ objpart, int nb1,
                             const float* __restrict__ blockpart, int bpl2,
                             float* __restrict__ out, int B)
{
    __shared__ float s[NT1];
    int tid = threadIdx.x;

    float v = 0.0f;
    for (int i = tid; i < nb1; i += NT1) v += objpart[i];
    float objsum = block_reduce<NT1>(v, s);

    float corrsum;
    {
        float v2 = 0.0f;
        int nbk = 3 * bpl2;
        for (int i = tid; i < nbk; i += NT1) v2 += blockpart[(size_t)i * 4 + 3];
        corrsum = block_reduce<NT1>(v2, s);
    }

    float r_lb[3], r_cnt[3], r_cls[3];
    for (int L = 0; L < 3; ++L) {
        float v2 = 0.0f;
        for (int i = tid; i < bpl2; i += NT1) v2 += blockpart[(size_t)(L * bpl2 + i) * 4 + 0];
        r_lb[L] = block_reduce<NT1>(v2, s);
        v2 = 0.0f;
        for (int i = tid; i < bpl2; i += NT1) v2 += blockpart[(size_t)(L * bpl2 + i) * 4 + 1];
        r_cnt[L] = block_reduce<NT1>(v2, s);
        v2 = 0.0f;
        for (int i = tid; i < bpl2; i += NT1) v2 += blockpart[(size_t)(L * bpl2 + i) * 4 + 2];
        r_cls[L] = block_reduce<NT1>(v2, s);
    }

    if (tid == 0) {
        float lobj = objsum - corrsum;
        float lb = 0.0f, lc = 0.0f;
        for (int L = 0; L < 3; ++L) {
            if (r_cnt[L] > 0.0f) {
                lb += r_lb[L] / fmaxf(r_cnt[L], 1.0f);
                lc += r_cls[L] / fmaxf(r_cnt[L] * 80.0f, 1.0f);
            }
        }
        out[0] = (0.05f * lb + lobj + 0.5f * lc) * (float)B;
    }
}

extern "C" void kernel_launch(void* const* d_in, const int* in_sizes, int n_in,
                              void* d_out, int out_size, void* d_ws, size_t ws_size,
                              hipStream_t stream) {
    const float* pred0 = (const float*)d_in[0];
    const float* pred1 = (const float*)d_in[1];
    const float* pred2 = (const float*)d_in[2];
    const float* targets = (const float*)d_in[3];

    int B = in_sizes[0] / (3 * 80 * 80 * 85);
    int nt = in_sizes[3] / 6;
    int n0 = B * 3 * 80 * 80;
    int n1 = B * 3 * 40 * 40;
    int n2 = B * 3 * 20 * 20;
    int N = n0 + n1 + n2;
    int NB1 = (N + NT1 - 1) / NT1;
    int perLayer = 15 * nt;
    int bpl2 = (perLayer + 15) / 16;        // 16 wave-entries per 1024-thr block
    int grid2 = 3 * bpl2;

    float* tobj = (float*)d_ws;
    float* objpart = tobj + N;
    float* blockpart = objpart + NB1;

    stream_kernel<<<NB1, NT1, 0, stream>>>(
        pred0, pred1, pred2, tobj, objpart, n0, n1, n2);
    entry_kernel<<<grid2, NT2, 0, stream>>>(
        pred0, pred1, pred2, targets, nt, bpl2, tobj, blockpart, n0, n1, n2);
    final_kernel<<<1, NT1, 0, stream>>>(
        objpart, NB1, blockpart, bpl2, (float*)d_out, B);
}